// Round 25
// baseline (27.805 us; speedup 1.0000x reference)
//
#include <hip/hip_runtime.h>
#include <math.h>

#define NBANDS 5
#define T_TILE 8
#define PFUNC_ELEMS (32*128*64*64)
#define LOG2E 1.4426950408889634f

// DPP segmented sum over each aligned 8-lane group (VALU pipe, no DS pipe):
//   0xB1 = quad_perm[1,0,3,2] (xor 1), 0x4E = quad_perm[2,3,0,1] (xor 2),
//   0x141 = row_half_mirror (pairs the two quads of each 8-lane group)
#define DPP_ADD(x, ctrl) \
    ((x) + __int_as_float(__builtin_amdgcn_update_dpp(0, __float_as_int(x), (ctrl), 0xF, 0xF, true)))

__global__ __launch_bounds__(512) void bfp_kernel(
        const float* __restrict__ x,      // (32,5,64,128)
        const float* __restrict__ adj,    // (64,64), values in {0,1}
        const float* __restrict__ amask,  // (32,128,5)
        const float* __restrict__ alpha,  // (32,128,5)
        const float* __restrict__ We,     // (5,64)
        const float* __restrict__ be,     // (5,64)
        const float* __restrict__ Wq,     // (16,64)
        const float* __restrict__ Wk,     // (16,64)
        float* __restrict__ out) {
    // 512 blocks; XCD-bijective swizzle (512 % 8 == 0); 2 blocks per CU
    const int bid = blockIdx.x;
    const int blk = (bid & 7) * 64 + (bid >> 3);
    const int bt0 = blk * T_TILE;
    const int b = bt0 >> 7;
    const int t0 = bt0 & 127;        // multiple of 8
    const int tid = threadIdx.x;

    __shared__ __align__(16) float x_s[T_TILE][NBANDS][64];
    __shared__ float xbar_s[T_TILE][NBANDS];
    __shared__ float w_s[T_TILE][NBANDS], mask_s[T_TILE][NBANDS];
    __shared__ float acw_s[NBANDS], bcw_s[NBANDS], bmax_s[NBANDS];

    const int i = tid >> 3;          // output row 0..63
    // contiguous-store column mapping (R20): thread q=(tid&7) owns cols
    // {4q..4q+3} and {32+4q..32+4q+3}; each store's 8-lane group = 128 B span.
    const int jA = (tid & 7) << 2;
    const int jB = jA + 32;

    // adjacency quads for both column groups (raw 0/1 multiplicative mask)
    const float4 a0 = *(const float4*)(adj + i * 64 + jA);
    const float4 a1 = *(const float4*)(adj + i * 64 + jB);

    // issue x staging loads early (waves 0..4): t0..t0+7 as two float4s
    float4 xs0, xs1;
    if (tid < NBANDS * 64) {
        const float* xp = x + ((size_t)b * 320 + tid) * 128 + t0;
        xs0 = *(const float4*)(xp);
        xs1 = *(const float4*)(xp + 4);
    }

    // amask/alpha staging on wave 7 (waves 0-4 run fused prep below)
    if (tid >= 512 - T_TILE * NBANDS) {
        const int idx = tid - (512 - T_TILE * NBANDS);      // 0..39
        const size_t base = ((size_t)b * 128 + t0) * NBANDS;
        const int t = idx / NBANDS, n = idx % NBANDS;
        float mk = amask[base + idx];
        mask_s[t][n] = mk;
        w_s[t][n] = alpha[base + idx] * mk;
    }

    // fused prep: wave w (0..4) computes band w's AC/BC
    {
        const int wvid = tid >> 6;
        const int lane = tid & 63;
        if (wvid < NBANDS) {
            const int n = wvid;
            const int s = lane >> 2;          // d_s index 0..15
            const int d0c = (lane & 3) * 16;  // d-chunk
            float u = 0.f, v = 0.f, w = 0.f;
            #pragma unroll
            for (int dd = 0; dd < 16; ++dd) {
                int d = d0c + dd;
                float we = We[n * 64 + d], bb = be[n * 64 + d];
                float wq = Wq[s * 64 + d], wk = Wk[s * 64 + d];
                u = fmaf(wq, we, u);   // A_s partial
                v = fmaf(wk, we, v);   // C_s partial
                w = fmaf(wq, bb, w);   // B_s partial
            }
            #pragma unroll
            for (int mk = 1; mk <= 2; mk <<= 1) {   // complete quads over d-chunks
                u += __shfl_xor(u, mk);
                v += __shfl_xor(v, mk);
                w += __shfl_xor(w, mk);
            }
            float ac = u * v, bc = w * v;           // A_s*C_s, B_s*C_s
            #pragma unroll
            for (int mk = 4; mk <= 32; mk <<= 1) {  // sum over the 16 s (each once)
                ac += __shfl_xor(ac, mk);
                bc += __shfl_xor(bc, mk);
            }
            if (lane == 0) {
                acw_s[n] = 0.25f * LOG2E * ac;  // 1/sqrt(d_s) * log2e folded
                bcw_s[n] = 0.25f * LOG2E * bc;
            }
        }
    }

    // write staged x to LDS + per-band absmax bound B_n + ALL 8 xbar sums,
    // computed on in-register values pre-barrier (R23/R24 pattern)
    if (tid < NBANDS * 64) {
        const int n = tid >> 6, c = tid & 63;
        x_s[0][n][c] = xs0.x;
        x_s[1][n][c] = xs0.y;
        x_s[2][n][c] = xs0.z;
        x_s[3][n][c] = xs0.w;
        x_s[4][n][c] = xs1.x;
        x_s[5][n][c] = xs1.y;
        x_s[6][n][c] = xs1.z;
        x_s[7][n][c] = xs1.w;
        float am = fmaxf(fmaxf(fmaxf(fabsf(xs0.x), fabsf(xs0.y)),
                               fmaxf(fabsf(xs0.z), fabsf(xs0.w))),
                         fmaxf(fmaxf(fabsf(xs1.x), fabsf(xs1.y)),
                               fmaxf(fabsf(xs1.z), fabsf(xs1.w))));
        float s0 = xs0.x, s1 = xs0.y, s2 = xs0.z, s3 = xs0.w;
        float s4 = xs1.x, s5 = xs1.y, s6 = xs1.z, s7 = xs1.w;
        #pragma unroll
        for (int mk = 32; mk >= 1; mk >>= 1) {
            s0 += __shfl_xor(s0, mk);
            s1 += __shfl_xor(s1, mk);
            s2 += __shfl_xor(s2, mk);
            s3 += __shfl_xor(s3, mk);
            s4 += __shfl_xor(s4, mk);
            s5 += __shfl_xor(s5, mk);
            s6 += __shfl_xor(s6, mk);
            s7 += __shfl_xor(s7, mk);
            am = fmaxf(am, __shfl_xor(am, mk));
        }
        if (c == 0) {
            bmax_s[n] = am;                    // max|x| over band n's 8x64 tile
            xbar_s[0][n] = s0 * (1.f / 64.f);
            xbar_s[1][n] = s1 * (1.f / 64.f);
            xbar_s[2][n] = s2 * (1.f / 64.f);
            xbar_s[3][n] = s3 * (1.f / 64.f);
            xbar_s[4][n] = s4 * (1.f / 64.f);
            xbar_s[5][n] = s5 * (1.f / 64.f);
            xbar_s[6][n] = s6 * (1.f / 64.f);
            xbar_s[7][n] = s7 * (1.f / 64.f);
        }
    }
    __syncthreads();   // the ONLY barrier

    // embeddings_mean for 8 t's (all 512 threads, one (t,d) each)
    {
        const int t = tid >> 6, d = tid & 63;
        float cnt = 0.f, accm = 0.f;
        #pragma unroll
        for (int n = 0; n < NBANDS; ++n) {
            cnt += mask_s[t][n];
            accm += mask_s[t][n] * fmaf(xbar_s[t][n], We[n * 64 + d], be[n * 64 + d]);
        }
        out[PFUNC_ELEMS + (size_t)(bt0 + t) * 64 + d] = accm / fmaxf(cnt, 1.f);
    }

    for (int t = 0; t < T_TILE; ++t) {
        // burst all LDS reads for this t: 10x ds_read_b128 + 5 scalars in flight
        float4 xv0[NBANDS], xv1[NBANDS];
        float gi[NBANDS];
        #pragma unroll
        for (int n = 0; n < NBANDS; ++n) {
            xv0[n] = *(const float4*)(&x_s[t][n][jA]);
            xv1[n] = *(const float4*)(&x_s[t][n][jB]);
            gi[n]  = x_s[t][n][i];
        }

        float acc[8];
        #pragma unroll
        for (int jj = 0; jj < 8; ++jj) acc[jj] = 0.f;

        #pragma unroll
        for (int n = 0; n < NBANDS; ++n) {
            // base-2 logits coefficient (0.25*log2e folded into acw/bcw)
            const float g2 = fmaf(acw_s[n], gi[n], bcw_s[n]);
            // conservative bound: |g2|*B_n >= g2*x_j for all j -> exp2 args <= 0;
            // self-loop keeps Z >= exp2(-2|g2|B), far above f32 underflow (R17/R23 verified)
            const float negm = -fabsf(g2) * bmax_s[n];
            float e0 = __builtin_amdgcn_exp2f(fmaf(g2, xv0[n].x, negm));
            float e1 = __builtin_amdgcn_exp2f(fmaf(g2, xv0[n].y, negm));
            float e2 = __builtin_amdgcn_exp2f(fmaf(g2, xv0[n].z, negm));
            float e3 = __builtin_amdgcn_exp2f(fmaf(g2, xv0[n].w, negm));
            float e4 = __builtin_amdgcn_exp2f(fmaf(g2, xv1[n].x, negm));
            float e5 = __builtin_amdgcn_exp2f(fmaf(g2, xv1[n].y, negm));
            float e6 = __builtin_amdgcn_exp2f(fmaf(g2, xv1[n].z, negm));
            float e7 = __builtin_amdgcn_exp2f(fmaf(g2, xv1[n].w, negm));
            // masked Z via two fma chains; the 8-lane group jointly covers all
            // 64 cols, so the DPP reduce still yields the full row sum.
            float z0 = e0 * a0.x;
            z0 = fmaf(e1, a0.y, z0);
            z0 = fmaf(e2, a0.z, z0);
            z0 = fmaf(e3, a0.w, z0);
            float z1 = e4 * a1.x;
            z1 = fmaf(e5, a1.y, z1);
            z1 = fmaf(e6, a1.z, z1);
            z1 = fmaf(e7, a1.w, z1);
            float Z = z0 + z1;
            Z = DPP_ADD(Z, 0xB1);    // + lane^1
            Z = DPP_ADD(Z, 0x4E);    // + lane^2
            Z = DPP_ADD(Z, 0x141);   // + mirrored quad (8-lane group total)
            const float sc = w_s[t][n] * __builtin_amdgcn_rcpf(fmaxf(Z, 1e-30f));
            // unmasked accumulate; mask applied once at the store
            acc[0] = fmaf(e0, sc, acc[0]);
            acc[1] = fmaf(e1, sc, acc[1]);
            acc[2] = fmaf(e2, sc, acc[2]);
            acc[3] = fmaf(e3, sc, acc[3]);
            acc[4] = fmaf(e4, sc, acc[4]);
            acc[5] = fmaf(e5, sc, acc[5]);
            acc[6] = fmaf(e6, sc, acc[6]);
            acc[7] = fmaf(e7, sc, acc[7]);
        }

        // apply adjacency mask once; PLAIN stores (A/B vs R24's nt):
        // contiguous-lane layout means L2 assembles full 64 B lines and
        // drains asynchronously — testing whether nt's L2-bypass was
        // actually the R20 win or just the lane remap.
        float4* outp0 = (float4*)(out + ((size_t)(bt0 + t) * 64 + i) * 64 + jA);
        float4* outp1 = (float4*)(out + ((size_t)(bt0 + t) * 64 + i) * 64 + jB);
        *outp0 = make_float4(acc[0] * a0.x, acc[1] * a0.y, acc[2] * a0.z, acc[3] * a0.w);
        *outp1 = make_float4(acc[4] * a1.x, acc[5] * a1.y, acc[6] * a1.z, acc[7] * a1.w);
    }
}

extern "C" void kernel_launch(void* const* d_in, const int* in_sizes, int n_in,
                              void* d_out, int out_size, void* d_ws, size_t ws_size,
                              hipStream_t stream) {
    const float* x     = (const float*)d_in[0];
    const float* adj   = (const float*)d_in[1];
    const float* amask = (const float*)d_in[2];
    const float* alpha = (const float*)d_in[3];
    const float* We    = (const float*)d_in[4];
    const float* be    = (const float*)d_in[5];
    const float* Wq    = (const float*)d_in[6];
    const float* Wk    = (const float*)d_in[7];
    float* out = (float*)d_out;

    bfp_kernel<<<512, 512, 0, stream>>>(x, adj, amask, alpha, We, be, Wq, Wk, out);
}

// Round 26
// 26.271 us; speedup vs baseline: 1.0584x; 1.0584x over previous
//
#include <hip/hip_runtime.h>
#include <math.h>

#define NBANDS 5
#define T_TILE 8
#define PFUNC_ELEMS (32*128*64*64)
#define LOG2E 1.4426950408889634f

typedef __attribute__((ext_vector_type(4))) float f32x4;

// DPP segmented sum over each aligned 8-lane group (VALU pipe, no DS pipe):
//   0xB1 = quad_perm[1,0,3,2] (xor 1), 0x4E = quad_perm[2,3,0,1] (xor 2),
//   0x141 = row_half_mirror (pairs the two quads of each 8-lane group)
#define DPP_ADD(x, ctrl) \
    ((x) + __int_as_float(__builtin_amdgcn_update_dpp(0, __float_as_int(x), (ctrl), 0xF, 0xF, true)))

__global__ __launch_bounds__(512) void bfp_kernel(
        const float* __restrict__ x,      // (32,5,64,128)
        const float* __restrict__ adj,    // (64,64), values in {0,1}
        const float* __restrict__ amask,  // (32,128,5)
        const float* __restrict__ alpha,  // (32,128,5)
        const float* __restrict__ We,     // (5,64)
        const float* __restrict__ be,     // (5,64)
        const float* __restrict__ Wq,     // (16,64)
        const float* __restrict__ Wk,     // (16,64)
        float* __restrict__ out) {
    // 512 blocks; XCD-bijective swizzle (512 % 8 == 0); 2 blocks per CU
    const int bid = blockIdx.x;
    const int blk = (bid & 7) * 64 + (bid >> 3);
    const int bt0 = blk * T_TILE;
    const int b = bt0 >> 7;
    const int t0 = bt0 & 127;        // multiple of 8
    const int tid = threadIdx.x;

    __shared__ __align__(16) float x_s[T_TILE][NBANDS][64];
    __shared__ float xbar_s[T_TILE][NBANDS];
    __shared__ float w_s[T_TILE][NBANDS], mask_s[T_TILE][NBANDS];
    __shared__ float acw_s[NBANDS], bcw_s[NBANDS], bmax_s[NBANDS];

    const int i = tid >> 3;          // output row 0..63
    // contiguous-store column mapping (R20): thread q=(tid&7) owns cols
    // {4q..4q+3} and {32+4q..32+4q+3}; each store's 8-lane group = 128 B span.
    const int jA = (tid & 7) << 2;
    const int jB = jA + 32;

    // adjacency quads for both column groups (raw 0/1 multiplicative mask)
    const float4 a0 = *(const float4*)(adj + i * 64 + jA);
    const float4 a1 = *(const float4*)(adj + i * 64 + jB);

    // issue x staging loads early (waves 0..4): t0..t0+7 as two float4s
    float4 xs0, xs1;
    if (tid < NBANDS * 64) {
        const float* xp = x + ((size_t)b * 320 + tid) * 128 + t0;
        xs0 = *(const float4*)(xp);
        xs1 = *(const float4*)(xp + 4);
    }

    // amask/alpha staging on wave 7 (waves 0-4 run fused prep below)
    if (tid >= 512 - T_TILE * NBANDS) {
        const int idx = tid - (512 - T_TILE * NBANDS);      // 0..39
        const size_t base = ((size_t)b * 128 + t0) * NBANDS;
        const int t = idx / NBANDS, n = idx % NBANDS;
        float mk = amask[base + idx];
        mask_s[t][n] = mk;
        w_s[t][n] = alpha[base + idx] * mk;
    }

    // fused prep: wave w (0..4) computes band w's AC/BC
    {
        const int wvid = tid >> 6;
        const int lane = tid & 63;
        if (wvid < NBANDS) {
            const int n = wvid;
            const int s = lane >> 2;          // d_s index 0..15
            const int d0c = (lane & 3) * 16;  // d-chunk
            float u = 0.f, v = 0.f, w = 0.f;
            #pragma unroll
            for (int dd = 0; dd < 16; ++dd) {
                int d = d0c + dd;
                float we = We[n * 64 + d], bb = be[n * 64 + d];
                float wq = Wq[s * 64 + d], wk = Wk[s * 64 + d];
                u = fmaf(wq, we, u);   // A_s partial
                v = fmaf(wk, we, v);   // C_s partial
                w = fmaf(wq, bb, w);   // B_s partial
            }
            #pragma unroll
            for (int mk = 1; mk <= 2; mk <<= 1) {   // complete quads over d-chunks
                u += __shfl_xor(u, mk);
                v += __shfl_xor(v, mk);
                w += __shfl_xor(w, mk);
            }
            float ac = u * v, bc = w * v;           // A_s*C_s, B_s*C_s
            #pragma unroll
            for (int mk = 4; mk <= 32; mk <<= 1) {  // sum over the 16 s (each once)
                ac += __shfl_xor(ac, mk);
                bc += __shfl_xor(bc, mk);
            }
            if (lane == 0) {
                acw_s[n] = 0.25f * LOG2E * ac;  // 1/sqrt(d_s) * log2e folded
                bcw_s[n] = 0.25f * LOG2E * bc;
            }
        }
    }

    // write staged x to LDS + per-band absmax bound B_n + ALL 8 xbar sums,
    // computed on in-register values pre-barrier (R23/R24 pattern)
    if (tid < NBANDS * 64) {
        const int n = tid >> 6, c = tid & 63;
        x_s[0][n][c] = xs0.x;
        x_s[1][n][c] = xs0.y;
        x_s[2][n][c] = xs0.z;
        x_s[3][n][c] = xs0.w;
        x_s[4][n][c] = xs1.x;
        x_s[5][n][c] = xs1.y;
        x_s[6][n][c] = xs1.z;
        x_s[7][n][c] = xs1.w;
        float am = fmaxf(fmaxf(fmaxf(fabsf(xs0.x), fabsf(xs0.y)),
                               fmaxf(fabsf(xs0.z), fabsf(xs0.w))),
                         fmaxf(fmaxf(fabsf(xs1.x), fabsf(xs1.y)),
                               fmaxf(fabsf(xs1.z), fabsf(xs1.w))));
        float s0 = xs0.x, s1 = xs0.y, s2 = xs0.z, s3 = xs0.w;
        float s4 = xs1.x, s5 = xs1.y, s6 = xs1.z, s7 = xs1.w;
        #pragma unroll
        for (int mk = 32; mk >= 1; mk >>= 1) {
            s0 += __shfl_xor(s0, mk);
            s1 += __shfl_xor(s1, mk);
            s2 += __shfl_xor(s2, mk);
            s3 += __shfl_xor(s3, mk);
            s4 += __shfl_xor(s4, mk);
            s5 += __shfl_xor(s5, mk);
            s6 += __shfl_xor(s6, mk);
            s7 += __shfl_xor(s7, mk);
            am = fmaxf(am, __shfl_xor(am, mk));
        }
        if (c == 0) {
            bmax_s[n] = am;                    // max|x| over band n's 8x64 tile
            xbar_s[0][n] = s0 * (1.f / 64.f);
            xbar_s[1][n] = s1 * (1.f / 64.f);
            xbar_s[2][n] = s2 * (1.f / 64.f);
            xbar_s[3][n] = s3 * (1.f / 64.f);
            xbar_s[4][n] = s4 * (1.f / 64.f);
            xbar_s[5][n] = s5 * (1.f / 64.f);
            xbar_s[6][n] = s6 * (1.f / 64.f);
            xbar_s[7][n] = s7 * (1.f / 64.f);
        }
    }
    __syncthreads();   // the ONLY barrier

    // embeddings_mean for 8 t's (all 512 threads, one (t,d) each)
    {
        const int t = tid >> 6, d = tid & 63;
        float cnt = 0.f, accm = 0.f;
        #pragma unroll
        for (int n = 0; n < NBANDS; ++n) {
            cnt += mask_s[t][n];
            accm += mask_s[t][n] * fmaf(xbar_s[t][n], We[n * 64 + d], be[n * 64 + d]);
        }
        out[PFUNC_ELEMS + (size_t)(bt0 + t) * 64 + d] = accm / fmaxf(cnt, 1.f);
    }

    for (int t = 0; t < T_TILE; ++t) {
        // burst all LDS reads for this t: 10x ds_read_b128 + 5 scalars in flight
        float4 xv0[NBANDS], xv1[NBANDS];
        float gi[NBANDS];
        #pragma unroll
        for (int n = 0; n < NBANDS; ++n) {
            xv0[n] = *(const float4*)(&x_s[t][n][jA]);
            xv1[n] = *(const float4*)(&x_s[t][n][jB]);
            gi[n]  = x_s[t][n][i];
        }

        float acc[8];
        #pragma unroll
        for (int jj = 0; jj < 8; ++jj) acc[jj] = 0.f;

        #pragma unroll
        for (int n = 0; n < NBANDS; ++n) {
            // base-2 logits coefficient (0.25*log2e folded into acw/bcw)
            const float g2 = fmaf(acw_s[n], gi[n], bcw_s[n]);
            // conservative bound: |g2|*B_n >= g2*x_j for all j -> exp2 args <= 0;
            // self-loop keeps Z >= exp2(-2|g2|B), far above f32 underflow (R17/R23 verified)
            const float negm = -fabsf(g2) * bmax_s[n];
            float e0 = __builtin_amdgcn_exp2f(fmaf(g2, xv0[n].x, negm));
            float e1 = __builtin_amdgcn_exp2f(fmaf(g2, xv0[n].y, negm));
            float e2 = __builtin_amdgcn_exp2f(fmaf(g2, xv0[n].z, negm));
            float e3 = __builtin_amdgcn_exp2f(fmaf(g2, xv0[n].w, negm));
            float e4 = __builtin_amdgcn_exp2f(fmaf(g2, xv1[n].x, negm));
            float e5 = __builtin_amdgcn_exp2f(fmaf(g2, xv1[n].y, negm));
            float e6 = __builtin_amdgcn_exp2f(fmaf(g2, xv1[n].z, negm));
            float e7 = __builtin_amdgcn_exp2f(fmaf(g2, xv1[n].w, negm));
            // masked Z via two fma chains; the 8-lane group jointly covers all
            // 64 cols, so the DPP reduce still yields the full row sum.
            float z0 = e0 * a0.x;
            z0 = fmaf(e1, a0.y, z0);
            z0 = fmaf(e2, a0.z, z0);
            z0 = fmaf(e3, a0.w, z0);
            float z1 = e4 * a1.x;
            z1 = fmaf(e5, a1.y, z1);
            z1 = fmaf(e6, a1.z, z1);
            z1 = fmaf(e7, a1.w, z1);
            float Z = z0 + z1;
            Z = DPP_ADD(Z, 0xB1);    // + lane^1
            Z = DPP_ADD(Z, 0x4E);    // + lane^2
            Z = DPP_ADD(Z, 0x141);   // + mirrored quad (8-lane group total)
            const float sc = w_s[t][n] * __builtin_amdgcn_rcpf(fmaxf(Z, 1e-30f));
            // unmasked accumulate; mask applied once at the store
            acc[0] = fmaf(e0, sc, acc[0]);
            acc[1] = fmaf(e1, sc, acc[1]);
            acc[2] = fmaf(e2, sc, acc[2]);
            acc[3] = fmaf(e3, sc, acc[3]);
            acc[4] = fmaf(e4, sc, acc[4]);
            acc[5] = fmaf(e5, sc, acc[5]);
            acc[6] = fmaf(e6, sc, acc[6]);
            acc[7] = fmaf(e7, sc, acc[7]);
        }

        // apply adjacency mask once; nt stores form FULL 64 B lines
        // (A/B verified: nt = 26.3 µs vs plain = 27.8 µs — L2 bypass wins
        // against the harness's dirty-L2 background)
        float* rowp = out + ((size_t)(bt0 + t) * 64 + i) * 64;
        f32x4 o0 = {acc[0] * a0.x, acc[1] * a0.y, acc[2] * a0.z, acc[3] * a0.w};
        f32x4 o1 = {acc[4] * a1.x, acc[5] * a1.y, acc[6] * a1.z, acc[7] * a1.w};
        __builtin_nontemporal_store(o0, (f32x4*)(rowp + jA));
        __builtin_nontemporal_store(o1, (f32x4*)(rowp + jB));
    }
}

extern "C" void kernel_launch(void* const* d_in, const int* in_sizes, int n_in,
                              void* d_out, int out_size, void* d_ws, size_t ws_size,
                              hipStream_t stream) {
    const float* x     = (const float*)d_in[0];
    const float* adj   = (const float*)d_in[1];
    const float* amask = (const float*)d_in[2];
    const float* alpha = (const float*)d_in[3];
    const float* We    = (const float*)d_in[4];
    const float* be    = (const float*)d_in[5];
    const float* Wq    = (const float*)d_in[6];
    const float* Wk    = (const float*)d_in[7];
    float* out = (float*)d_out;

    bfp_kernel<<<512, 512, 0, stream>>>(x, adj, amask, alpha, We, be, Wq, Wk, out);
}